// Round 5
// baseline (244.584 us; speedup 1.0000x reference)
//
#include <hip/hip_runtime.h>
#include <math.h>

// Problem constants (fixed by setup_inputs): B=512, C=3000, T=25.
#define B_ 512
#define C_ 3000
#define T_ 25
#define C4_ (C_ / 4)            // 750 float4 per row
#define TG_ 5                   // distorted t's per block

// Grid = 512 * 6 blocks of 256 threads. g = blockIdx>>9 in [0,5]:
//   g<5 : t = 5g..5g+4 (15 noise float4 loads issued up-front, pred/true
//         register-resident, 10 accumulators -> deep MLP + 12 blocks/CU TLP)
//   g==5: undistorted row (x = pred, no noise)
// No-max logsumexp (inputs bounded, |x| <= ~11) -> three flat sums per t,
// no loop-carried chains anywhere.
__global__ __launch_bounds__(256, 4) void ace_rows(
    const float* __restrict__ logit_var,   // [B,1]
    const float* __restrict__ pred,        // [B,C]
    const float* __restrict__ tru,         // [B,C]
    const float* __restrict__ noise,       // [T,B,C]
    float* __restrict__ dsum)              // [T+1] per-t sum over b of row loss
{
    const int tid = threadIdx.x;
    const int b   = blockIdx.x & 511;
    const int g   = blockIdx.x >> 9;       // 0..5

    const float4* __restrict__ p4 = (const float4*)(pred + (size_t)b * C_);
    const float4* __restrict__ t4 = (const float4*)(tru  + (size_t)b * C_);

    const int  i0   = tid;
    const int  i1   = tid + 256;
    const bool has2 = (tid < C4_ - 512);        // tid < 238
    const int  i2   = has2 ? tid + 512 : tid;   // clamped (safe) address

    float4 pv0 = p4[i0], pv1 = p4[i1], pv2 = p4[i2];
    float4 tv0 = t4[i0], tv1 = t4[i1], tv2 = t4[i2];

    float p[12], tr[12];
    p[0]=pv0.x; p[1]=pv0.y; p[2]=pv0.z; p[3]=pv0.w;
    p[4]=pv1.x; p[5]=pv1.y; p[6]=pv1.z; p[7]=pv1.w;
    p[8]=pv2.x; p[9]=pv2.y; p[10]=pv2.z; p[11]=pv2.w;
    tr[0]=tv0.x; tr[1]=tv0.y; tr[2]=tv0.z; tr[3]=tv0.w;
    tr[4]=tv1.x; tr[5]=tv1.y; tr[6]=tv1.z; tr[7]=tv1.w;
    tr[8]=tv2.x; tr[9]=tv2.y; tr[10]=tv2.z; tr[11]=tv2.w;
    if (!has2) {
        // poison tail lanes: exp(-1e30)=0, tr=0 kills dot/Tm contributions.
#pragma unroll
        for (int j = 8; j < 12; ++j) { p[j] = -1e30f; tr[j] = 0.f; }
    }

    float Tm = 0.f;
#pragma unroll
    for (int j = 0; j < 12; ++j) Tm += tr[j];

    float S[TG_], D[TG_];
#pragma unroll
    for (int k = 0; k < TG_; ++k) { S[k] = 0.f; D[k] = 0.f; }

    if (g < 5) {
        const float stdv = sqrtf(logit_var[b]);
        const int   t0   = g * TG_;
        // Issue ALL 15 independent noise loads before any consumption.
        float4 nv0[TG_], nv1[TG_], nv2[TG_];
#pragma unroll
        for (int k = 0; k < TG_; ++k) {
            const float4* __restrict__ n4 =
                (const float4*)(noise + ((size_t)(t0 + k) * B_ + b) * (size_t)C_);
            nv0[k] = n4[i0]; nv1[k] = n4[i1]; nv2[k] = n4[i2];
        }
#pragma unroll
        for (int k = 0; k < TG_; ++k) {
            float n[12];
            n[0]=nv0[k].x; n[1]=nv0[k].y; n[2]=nv0[k].z; n[3]=nv0[k].w;
            n[4]=nv1[k].x; n[5]=nv1[k].y; n[6]=nv1[k].z; n[7]=nv1[k].w;
            n[8]=nv2[k].x; n[9]=nv2[k].y; n[10]=nv2[k].z; n[11]=nv2[k].w;
            float s_acc = 0.f, d_acc = 0.f;
#pragma unroll
            for (int j = 0; j < 12; ++j) {
                float x = fmaf(stdv, n[j], p[j]);   // tail: -1e30 -> exp 0
                s_acc += __expf(x);
                d_acc  = fmaf(x, tr[j], d_acc);
            }
            S[k] = s_acc; D[k] = d_acc;
        }
    } else {
        // undistorted row: x = pred
        float s_acc = 0.f, d_acc = 0.f;
#pragma unroll
        for (int j = 0; j < 12; ++j) {
            s_acc += __expf(p[j]);
            d_acc  = fmaf(p[j], tr[j], d_acc);
        }
        S[0] = s_acc; D[0] = d_acc;
    }

    // 64-lane butterfly reduction of Tm and the 5 (S,D) pairs.
    for (int off = 32; off > 0; off >>= 1) {
        Tm += __shfl_xor(Tm, off);
#pragma unroll
        for (int k = 0; k < TG_; ++k) {
            S[k] += __shfl_xor(S[k], off);
            D[k] += __shfl_xor(D[k], off);
        }
    }

    // Cross-wave combine via LDS.
    __shared__ float redS[TG_][4], redD[TG_][4], redTm[4];
    const int wave = tid >> 6, lane = tid & 63;
    if (lane == 0) {
        redTm[wave] = Tm;
#pragma unroll
        for (int k = 0; k < TG_; ++k) { redS[k][wave] = S[k]; redD[k][wave] = D[k]; }
    }
    __syncthreads();
    const int nt = (g < 5) ? TG_ : 1;
    if (tid < nt) {
        float Sa  = redS[tid][0] + redS[tid][1] + redS[tid][2] + redS[tid][3];
        float Da  = redD[tid][0] + redD[tid][1] + redD[tid][2] + redD[tid][3];
        float Tma = redTm[0] + redTm[1] + redTm[2] + redTm[3];
        float lse = logf(Sa);                    // no max shift needed
        const int t = (g < 5) ? (g * TG_ + tid) : T_;
        atomicAdd(&dsum[t], (lse * Tma - Da) * 0.1f);
    }
}

// Single wave: depressor reduction over B=512, per-t means, elu, final 4 outputs.
__global__ __launch_bounds__(64) void ace_final(
    const float* __restrict__ logit_var,
    const float* __restrict__ dsum,
    float* __restrict__ out)
{
    const int lane = threadIdx.x;

    float dep = 0.0f;
    for (int i = lane; i < B_; i += 64)
        dep += __expf(logit_var[i]) - 1.0f;

    const float undist = dsum[T_] * (1.0f / B_);
    float d  = (lane < T_) ? dsum[lane] * (1.0f / B_) : 0.0f;
    float el = 0.0f;
    if (lane < T_) {
        float x   = undist - d;
        float elu = (x > 0.0f) ? x : (__expf(x) - 1.0f);
        el = -elu;
    }

    for (int off = 32; off > 0; off >>= 1) {
        dep += __shfl_xor(dep, off);
        d   += __shfl_xor(d, off);
        el  += __shfl_xor(el, off);
    }

    if (lane == 0) {
        out[0] = d  * (1.0f / T_);   // gce_loss
        out[1] = el * (1.0f / T_);   // variance_loss
        out[2] = undist;             // undistorted_loss
        out[3] = dep * (1.0f / B_);  // variance_depressor
    }
}

extern "C" void kernel_launch(void* const* d_in, const int* in_sizes, int n_in,
                              void* d_out, int out_size, void* d_ws, size_t ws_size,
                              hipStream_t stream) {
    const float* logit_var = (const float*)d_in[0];  // [512,1]
    const float* pred      = (const float*)d_in[1];  // [512,3000]
    const float* tru       = (const float*)d_in[2];  // [512,3000]
    const float* noise     = (const float*)d_in[3];  // [25,512,3000]
    float* out  = (float*)d_out;                     // 4 fp32 scalars
    float* dsum = (float*)d_ws;                      // (T+1) fp32 accumulators

    hipMemsetAsync(dsum, 0, (T_ + 1) * sizeof(float), stream);
    ace_rows<<<B_ * 6, 256, 0, stream>>>(logit_var, pred, tru, noise, dsum);
    ace_final<<<1, 64, 0, stream>>>(logit_var, dsum, out);
}

// Round 6
// 229.817 us; speedup vs baseline: 1.0643x; 1.0643x over previous
//
#include <hip/hip_runtime.h>
#include <math.h>

// Problem constants (fixed by setup_inputs): B=512, C=3000, T=25.
#define B_ 512
#define C_ 3000
#define T_ 25
#define C4_ (C_ / 4)            // 750 float4 per row

typedef float v4f __attribute__((ext_vector_type(4)));

// One 256-thread block per batch row b (512 blocks). pred/true rows loaded
// ONCE into registers and reused across all 25 noise draws (byte-minimal:
// 166 MB total tier traffic — R4 structure, best total so far).
// R6 change: noise loads are NONTEMPORAL (read-once stream, 92% of bytes).
// R1-R5 all plateaued at ~3.0-3.3 TB/s read-tier rate regardless of
// occupancy/ILP structure; if that cap is L2-allocation work, nt dodges it.
// No-max logsumexp (inputs bounded, |x| <= ~11) -> flat sums, no chains.
__global__ __launch_bounds__(256, 2) void ace_rows(
    const float* __restrict__ logit_var,   // [B,1]
    const float* __restrict__ pred,        // [B,C]
    const float* __restrict__ tru,         // [B,C]
    const float* __restrict__ noise,       // [T,B,C]
    float* __restrict__ dsum)              // [T+1] per-t sum over b of row loss
{
    const int tid = threadIdx.x;
    const int b   = blockIdx.x;

    const float4* __restrict__ p4 = (const float4*)(pred + (size_t)b * C_);
    const float4* __restrict__ t4 = (const float4*)(tru  + (size_t)b * C_);

    const int  i0   = tid;
    const int  i1   = tid + 256;
    const bool has2 = (tid < C4_ - 512);        // tid < 238
    const int  i2   = has2 ? tid + 512 : tid;   // clamped (safe) address

    const float stdv = sqrtf(logit_var[b]);

    float4 pv0 = p4[i0], pv1 = p4[i1], pv2 = p4[i2];
    float4 tv0 = t4[i0], tv1 = t4[i1], tv2 = t4[i2];

    float p[12], tr[12];
    p[0]=pv0.x; p[1]=pv0.y; p[2]=pv0.z; p[3]=pv0.w;
    p[4]=pv1.x; p[5]=pv1.y; p[6]=pv1.z; p[7]=pv1.w;
    p[8]=pv2.x; p[9]=pv2.y; p[10]=pv2.z; p[11]=pv2.w;
    tr[0]=tv0.x; tr[1]=tv0.y; tr[2]=tv0.z; tr[3]=tv0.w;
    tr[4]=tv1.x; tr[5]=tv1.y; tr[6]=tv1.z; tr[7]=tv1.w;
    tr[8]=tv2.x; tr[9]=tv2.y; tr[10]=tv2.z; tr[11]=tv2.w;
    if (!has2) {
        // poison tail lanes: exp(-1e30)=0, tr=0 kills dot/Tm contributions.
#pragma unroll
        for (int j = 8; j < 12; ++j) { p[j] = -1e30f; tr[j] = 0.f; }
    }

    float S[T_ + 1], D[T_ + 1];
    float Tm = 0.f;
    // undistorted row (index T_): x = pred
    {
        float s_acc = 0.f, d_acc = 0.f;
#pragma unroll
        for (int j = 0; j < 12; ++j) {
            s_acc += __expf(p[j]);
            d_acc  = fmaf(p[j], tr[j], d_acc);
            Tm    += tr[j];
        }
        S[T_] = s_acc; D[T_] = d_acc;
    }

    const v4f* __restrict__ nb = (const v4f*)(noise + (size_t)b * C_);
#pragma unroll
    for (int t = 0; t < T_; ++t) {
        const v4f* __restrict__ n4 = nb + (size_t)t * (size_t)(B_ * C4_);
        // read-once stream: nontemporal (no L2 allocation / eviction work)
        v4f nv0 = __builtin_nontemporal_load(n4 + i0);
        v4f nv1 = __builtin_nontemporal_load(n4 + i1);
        v4f nv2 = __builtin_nontemporal_load(n4 + i2);
        float n[12];
        n[0]=nv0.x; n[1]=nv0.y; n[2]=nv0.z; n[3]=nv0.w;
        n[4]=nv1.x; n[5]=nv1.y; n[6]=nv1.z; n[7]=nv1.w;
        n[8]=nv2.x; n[9]=nv2.y; n[10]=nv2.z; n[11]=nv2.w;
        float s_acc = 0.f, d_acc = 0.f;
#pragma unroll
        for (int j = 0; j < 12; ++j) {
            float x = fmaf(stdv, n[j], p[j]);   // tail lanes: -1e30 -> exp 0
            s_acc += __expf(x);
            d_acc  = fmaf(x, tr[j], d_acc);
        }
        S[t] = s_acc; D[t] = d_acc;
    }

    // 64-lane butterfly reduction of Tm and all 26 (S,D) pairs.
    for (int off = 32; off > 0; off >>= 1) {
        Tm += __shfl_xor(Tm, off);
#pragma unroll
        for (int t = 0; t <= T_; ++t) {
            S[t] += __shfl_xor(S[t], off);
            D[t] += __shfl_xor(D[t], off);
        }
    }

    // Cross-wave combine via LDS; threads 0..25 finish their t.
    __shared__ float redS[T_ + 1][4], redD[T_ + 1][4], redTm[4];
    const int wave = tid >> 6, lane = tid & 63;
    if (lane == 0) {
        redTm[wave] = Tm;
#pragma unroll
        for (int t = 0; t <= T_; ++t) { redS[t][wave] = S[t]; redD[t][wave] = D[t]; }
    }
    __syncthreads();
    if (tid <= T_) {
        float Sa  = redS[tid][0] + redS[tid][1] + redS[tid][2] + redS[tid][3];
        float Da  = redD[tid][0] + redD[tid][1] + redD[tid][2] + redD[tid][3];
        float Tma = redTm[0] + redTm[1] + redTm[2] + redTm[3];
        float lse = logf(Sa);                    // no max shift needed
        atomicAdd(&dsum[tid], (lse * Tma - Da) * 0.1f);
    }
}

// Single wave: depressor reduction over B=512, per-t means, elu, final 4 outputs.
__global__ __launch_bounds__(64) void ace_final(
    const float* __restrict__ logit_var,
    const float* __restrict__ dsum,
    float* __restrict__ out)
{
    const int lane = threadIdx.x;

    float dep = 0.0f;
    for (int i = lane; i < B_; i += 64)
        dep += __expf(logit_var[i]) - 1.0f;

    const float undist = dsum[T_] * (1.0f / B_);
    float d  = (lane < T_) ? dsum[lane] * (1.0f / B_) : 0.0f;
    float el = 0.0f;
    if (lane < T_) {
        float x   = undist - d;
        float elu = (x > 0.0f) ? x : (__expf(x) - 1.0f);
        el = -elu;
    }

    for (int off = 32; off > 0; off >>= 1) {
        dep += __shfl_xor(dep, off);
        d   += __shfl_xor(d, off);
        el  += __shfl_xor(el, off);
    }

    if (lane == 0) {
        out[0] = d  * (1.0f / T_);   // gce_loss
        out[1] = el * (1.0f / T_);   // variance_loss
        out[2] = undist;             // undistorted_loss
        out[3] = dep * (1.0f / B_);  // variance_depressor
    }
}

extern "C" void kernel_launch(void* const* d_in, const int* in_sizes, int n_in,
                              void* d_out, int out_size, void* d_ws, size_t ws_size,
                              hipStream_t stream) {
    const float* logit_var = (const float*)d_in[0];  // [512,1]
    const float* pred      = (const float*)d_in[1];  // [512,3000]
    const float* tru       = (const float*)d_in[2];  // [512,3000]
    const float* noise     = (const float*)d_in[3];  // [25,512,3000]
    float* out  = (float*)d_out;                     // 4 fp32 scalars
    float* dsum = (float*)d_ws;                      // (T+1) fp32 accumulators

    hipMemsetAsync(dsum, 0, (T_ + 1) * sizeof(float), stream);
    ace_rows<<<B_, 256, 0, stream>>>(logit_var, pred, tru, noise, dsum);
    ace_final<<<1, 64, 0, stream>>>(logit_var, dsum, out);
}